// Round 19
// baseline (150.030 us; speedup 1.0000x reference)
//
#include <hip/hip_runtime.h>
#include <hip/hip_bf16.h>
#include <cfloat>

#define N_TOK 8192
#define C_DIM 256
#define H_DIM 1024
#define E_ALL 32
#define E_RT  31
#define HS    128                     // h per image slice (prep granularity)
#define NSL   8                       // slices
#define TN    64                      // tokens per block (4 waves x 16)
#define HC2   32                      // h per step
#define NSTH  16                      // steps per H-half job
#define STEP_B16 16384                // bytes per weight-matrix step chunk
#define SLICE_B (HS * C_DIM * 2)      // 64 KB per slice
#define TG    32                      // tokens per gate block

// Yp geometry: 2 H-half banks of unweighted partials
#define YROWS 35072
#define YBANK ((size_t)YROWS * C_DIM)

// XCD-aware map geometry: slot s runs on XCD s%8 (round-robin dispatch)
#define NQ      8
#define QCAP    160
#define TAILN   256
#define MAPSLOTS (NQ * QCAP + TAILN)  // 1536

typedef __attribute__((ext_vector_type(8))) short bf16x8;
typedef __attribute__((ext_vector_type(4))) float f32x4;

__device__ __forceinline__ unsigned short f2bf(float f) {
    return __builtin_bit_cast(unsigned short, __float2bfloat16(f));
}
__device__ __forceinline__ float bf2f(unsigned short u) {
    unsigned int x = ((unsigned int)u) << 16;
    return __builtin_bit_cast(float, x);
}
__device__ __forceinline__ void gld16(void* lds, const void* g) {
    __builtin_amdgcn_global_load_lds(
        (const __attribute__((address_space(1))) void*)g,
        (__attribute__((address_space(3))) void*)lds, 16, 0, 0);
}

// ---------------------------------------------------------- fused front-end -
__device__ __forceinline__
void gate_body(char* smem, int blk,
               const float* __restrict__ x, const float* __restrict__ Wg,
               const float* __restrict__ ebias,
               float* __restrict__ rw, int* __restrict__ cnt,
               int* __restrict__ toks,
               int* __restrict__ se, int* __restrict__ sp, float* __restrict__ sw,
               unsigned short* __restrict__ xb)
{
    float* WgL = (float*)smem;                               // 32 KB [c*32+e]
    float (*xsW)[C_DIM] = (float(*)[C_DIM])(smem + 32768);   // 4 KB
    int*   lcnt = (int*)(smem + 36864);
    int*   gbase = lcnt + 32;
    int*   tokE  = gbase + 32;
    int*   tokLP = tokE + 96;
    float* tokW  = (float*)(tokLP + 96);

    const int n0  = blk * TG;
    const int tid = threadIdx.x;
    const int w    = tid >> 6;
    const int lane = tid & 63;
    const int e    = lane & 31;
    const int h    = lane >> 5;

    for (int i = tid; i < C_DIM * E_RT / 4; i += 256) {
        const float4 v = ((const float4*)Wg)[i];
        const int l = i * 4;
        #pragma unroll
        for (int j = 0; j < 4; ++j) {
            const int lj = l + j, c = lj / E_RT, ee = lj - c * E_RT;
            const float vv = (j == 0) ? v.x : (j == 1) ? v.y : (j == 2) ? v.z : v.w;
            WgL[c * 32 + ee] = vv;
        }
    }
    if (tid < E_RT) lcnt[tid] = 0;
    __syncthreads();

    const float eb = (e < E_RT) ? ebias[e] : 0.f;

    #pragma unroll 1
    for (int j = 0; j < 8; ++j) {
        const int n = n0 + w * 8 + j;
        const float4 xv = ((const float4*)(x + (size_t)n * C_DIM))[lane];
        ((float4*)xsW[w])[lane] = xv;
        {
            ushort4 b;
            b.x = f2bf(xv.x); b.y = f2bf(xv.y); b.z = f2bf(xv.z); b.w = f2bf(xv.w);
            ((ushort4*)(xb + (size_t)n * C_DIM))[lane] = b;
        }
        float p0 = 0.f, p1 = 0.f, p2 = 0.f, p3 = 0.f;
        const int cb = h * 128;
        #pragma unroll
        for (int c4 = 0; c4 < 32; ++c4) {
            const float4 xq = *(const float4*)&xsW[w][cb + c4 * 4];
            p0 = fmaf(xq.x, WgL[(cb + c4 * 4 + 0) * 32 + e], p0);
            p1 = fmaf(xq.y, WgL[(cb + c4 * 4 + 1) * 32 + e], p1);
            p2 = fmaf(xq.z, WgL[(cb + c4 * 4 + 2) * 32 + e], p2);
            p3 = fmaf(xq.w, WgL[(cb + c4 * 4 + 3) * 32 + e], p3);
        }
        float part = (p0 + p1) + (p2 + p3);
        part += __shfl_xor(part, 32);
        const float logit = (lane < E_RT) ? part : -FLT_MAX;

        float m = logit;
        for (int off = 32; off; off >>= 1) m = fmaxf(m, __shfl_xor(m, off));
        const float ev = (lane < E_RT) ? expf(logit - m) : 0.f;
        float sum = ev;
        for (int off = 32; off; off >>= 1) sum += __shfl_xor(sum, off);
        const float gate = ev / sum;
        const float biased = (lane < E_RT) ? gate + eb : -FLT_MAX;

        float val[3]; int idx[3];
        float cur = biased;
        #pragma unroll
        for (int k = 0; k < 3; ++k) {
            float mk = cur;
            for (int off = 32; off; off >>= 1) mk = fmaxf(mk, __shfl_xor(mk, off));
            unsigned long long ball = __ballot(cur == mk && lane < E_RT);
            int sel = __ffsll(ball) - 1;
            val[k] = mk; idx[k] = sel;
            if (lane == sel) cur = -FLT_MAX;
        }

        const float st = val[0] + val[1] + val[2];
        const float wr0 = val[0] / st * 0.75f;
        const float wr1 = val[1] / st * 0.75f;
        const float wr2 = val[2] / st * 0.75f;

        if (lane < E_ALL) {
            float v = 0.f;
            if (lane == 0)          v = 0.25f;
            if (lane == idx[0] + 1) v = wr0;
            if (lane == idx[1] + 1) v = wr1;
            if (lane == idx[2] + 1) v = wr2;
            rw[(size_t)n * E_ALL + lane] = v;
        }

        if (lane == 0) {
            const float wv[3] = {wr0, wr1, wr2};
            const int tl = w * 8 + j;
            #pragma unroll
            for (int k = 0; k < 3; ++k) {
                const int lp = atomicAdd(&lcnt[idx[k]], 1);
                tokE[tl * 3 + k] = idx[k];
                tokLP[tl * 3 + k] = lp;
                tokW[tl * 3 + k] = wv[k];
            }
        }
    }

    __syncthreads();
    if (tid < E_RT) gbase[tid] = atomicAdd(&cnt[tid], lcnt[tid]);
    __syncthreads();

    if (tid < TG) {
        const int n = n0 + tid;
        #pragma unroll
        for (int k = 0; k < 3; ++k) {
            const int e31 = tokE[tid * 3 + k];
            const int pos = gbase[e31] + tokLP[tid * 3 + k];
            toks[e31 * N_TOK + pos] = n;
            se[n * 3 + k] = e31;
            sp[n * 3 + k] = pos;
            sw[n * 3 + k] = tokW[tid * 3 + k];
        }
    }
}

__device__ __forceinline__
void prep_fc_body(char* smem, int unit,
                  const float* __restrict__ Wfc, unsigned short* __restrict__ img)
{
    const int s = unit & 7, e = unit >> 3;
    const int h0 = s * HS;
    unsigned short* tb = (unsigned short*)smem;
    const int tid = threadIdx.x;
    #pragma unroll
    for (int i = 0; i < 32; ++i) {
        const int fidx = i * 1024 + tid * 4;
        const int c = fidx >> 7, hh = fidx & 127;
        const float4 v = *(const float4*)(Wfc + ((size_t)e * C_DIM + c) * H_DIM + h0 + hh);
        ushort4 b;
        b.x = f2bf(v.x); b.y = f2bf(v.y); b.z = f2bf(v.z); b.w = f2bf(v.w);
        *(ushort4*)(tb + c * HS + hh) = b;
    }
    __syncthreads();
    const int lane = tid & 63, w = tid >> 6;
    const int l15 = lane & 15, kg = lane >> 4;
    unsigned short* dst = img + ((size_t)e * NSL + s) * (SLICE_B / 2);
    for (int li = w; li < 64; li += 4) {
        const int ct = li >> 3, ks = li & 7;      // ct-major
        bf16x8 v;
        #pragma unroll
        for (int j = 0; j < 8; ++j)
            v[j] = (short)tb[(ks * 32 + kg * 8 + j) * HS + ct * 16 + l15];
        *(bf16x8*)(dst + (size_t)li * 512 + lane * 8) = v;
    }
}

__device__ __forceinline__
void prep_pj_body(char* smem, int unit,
                  const float* __restrict__ Wpj, unsigned short* __restrict__ img)
{
    const int s = unit & 7, e = unit >> 3;
    const int h0 = s * HS;
    unsigned short* tb = (unsigned short*)smem;
    const int tid = threadIdx.x;
    #pragma unroll
    for (int i = 0; i < 32; ++i) {
        const int fidx = i * 1024 + tid * 4;
        const int r = fidx >> 8, cc = fidx & 255;
        const float4 v = *(const float4*)(Wpj + ((size_t)e * H_DIM + h0 + r) * C_DIM + cc);
        ushort4 b;
        b.x = f2bf(v.x); b.y = f2bf(v.y); b.z = f2bf(v.z); b.w = f2bf(v.w);
        *(ushort4*)(tb + r * C_DIM + cc) = b;
    }
    __syncthreads();
    const int lane = tid & 63, w = tid >> 6;
    const int l15 = lane & 15, kg = lane >> 4;
    unsigned short* dst = img + ((size_t)e * NSL + s) * (SLICE_B / 2);
    for (int li = w; li < 64; li += 4) {
        const int ks = li >> 4, ct = li & 15;
        bf16x8 v;
        #pragma unroll
        for (int j = 0; j < 8; ++j)
            v[j] = (short)tb[(ks * 32 + kg * 8 + j) * C_DIM + ct + l15 * 16];
        *(bf16x8*)(dst + (size_t)li * 512 + lane * 8) = v;
    }
}

__global__ __launch_bounds__(256)
void prep_gate(const float* __restrict__ x, const float* __restrict__ Wg,
               const float* __restrict__ ebias,
               float* __restrict__ rw, int* __restrict__ cnt,
               int* __restrict__ toks,
               int* __restrict__ se, int* __restrict__ sp, float* __restrict__ sw,
               unsigned short* __restrict__ xb,
               const float* __restrict__ Wfc, const float* __restrict__ Wpj,
               unsigned short* __restrict__ fc_img, unsigned short* __restrict__ pj_img)
{
    __shared__ char smem[65536];
    const int b = blockIdx.x;
    if (b < 256)      gate_body(smem, b, x, Wg, ebias, rw, cnt, toks, se, sp, sw, xb);
    else if (b < 512) prep_fc_body(smem, b - 256, Wfc, fc_img);
    else              prep_pj_body(smem, b - 512, Wpj, pj_img);
}

// ---- seg + XCD-aware map of (expert, 64-tok tile, H-half) jobs -------------
__global__ __launch_bounds__(64)
void finalize(const int* __restrict__ cnt, int* __restrict__ seg,
              unsigned int* __restrict__ map) {
    __shared__ int ntS[E_RT];
    __shared__ int qaS[E_RT * 2];
    __shared__ int jsS[E_RT * 2];
    __shared__ int segS[E_ALL];
    __shared__ int jposS[NQ];
    __shared__ int spillS;

    const int tid = threadIdx.x;

    for (int s = tid; s < MAPSLOTS; s += 64) map[s] = 0xFFFFFFFFu;
    if (tid < E_RT) ntS[tid] = (cnt[tid] + TN - 1) / TN;
    if (tid == 0) spillS = NQ * QCAP;
    __syncthreads();

    if (tid == 0) {
        int b = N_TOK;
        segS[0] = 0;
        for (int i = 0; i < E_RT; ++i) { segS[i + 1] = b; b += (cnt[i] + 63) & ~63; }
        for (int q = 0; q < NQ; ++q) jposS[q] = (2 * N_TOK / TN) / NQ;   // 32
        for (int j2 = 0; j2 < E_RT * 2; ++j2) {
            const int i = j2 >> 1;
            int q = 0;
            for (int j = 1; j < NQ; ++j) if (jposS[j] < jposS[q]) q = j;
            qaS[j2] = q;
            jsS[j2] = jposS[q];
            jposS[q] += ntS[i];
        }
    }
    __syncthreads();

    if (tid < E_ALL) seg[tid] = segS[tid];

    for (int cmb = tid; cmb < 2 * N_TOK / TN; cmb += 64) {
        const unsigned v = ((unsigned)(cmb & 1) << 16) | (unsigned)(cmb >> 1);
        map[(cmb / NQ) * NQ + (cmb % NQ)] = v;
    }

    if (tid < E_RT * 2) {
        const int i = tid >> 1, hf = tid & 1;
        const int q = qaS[tid], js = jsS[tid], ntv = ntS[i];
        for (int t = 0; t < ntv; ++t) {
            const unsigned v = ((unsigned)hf << 16) |
                               ((unsigned)(i + 1) << 8) | (unsigned)t;
            const int jrow = js + t;
            if (jrow < QCAP) map[jrow * NQ + q] = v;
            else {
                const int s = atomicAdd(&spillS, 1);
                if (s < MAPSLOTS) map[s] = v;
            }
        }
    }
}

// --- experts: R16 structure (fc dbuf + pj single, 52 KB, 3 blocks/CU) + step
//     PHASE ROTATION: co-resident blocks process H-steps in rotated order so
//     their stage (VMEM) and compute (LDS/MFMA) bursts anti-correlate --------
__global__ __launch_bounds__(256)
void expert_kernel(const unsigned short* __restrict__ xb,
                   const unsigned short* __restrict__ fc_img,
                   const unsigned short* __restrict__ pj_img,
                   const int* __restrict__ cnt,
                   const int* __restrict__ seg,
                   const int* __restrict__ toks,
                   const unsigned int* __restrict__ map,
                   unsigned short* __restrict__ Yp)
{
    const unsigned int mp = map[blockIdx.x];
    if (mp == 0xFFFFFFFFu) return;
    const int half = (mp >> 16) & 1;
    const int e = (mp >> 8) & 255;
    const int tstart = (int)(mp & 255u) * TN;
    const int count = (e == 0) ? N_TOK : cnt[e - 1];
    const int tend = min(tstart + TN, count);
    const int segbase = seg[e];

    __shared__ unsigned short fc0[STEP_B16 / 2];   // 16 KB
    __shared__ unsigned short fc1[STEP_B16 / 2];   // 16 KB
    __shared__ unsigned short pjS[STEP_B16 / 2];   // 16 KB (single buffer)
    __shared__ unsigned short Hsm[TN * HC2];       // 4 KB, wave-local rows

    const int tid  = threadIdx.x;
    const int lane = tid & 63;
    const int w    = tid >> 6;
    const int l15  = lane & 15;
    const int kg   = lane >> 4;

    const int p = tstart + w * 16 + l15;
    int tok = 0;
    if (p < tend) tok = (e == 0) ? p : toks[(e - 1) * N_TOK + p];

    bf16x8 aF[8];
    {
        const unsigned short* xr = xb + (size_t)tok * C_DIM + kg * 8;
        #pragma unroll
        for (int ks = 0; ks < 8; ++ks)
            aF[ks] = *(const bf16x8*)(xr + ks * 32);
    }

    f32x4 accP[16];
    #pragma unroll
    for (int i = 0; i < 16; ++i) accP[i] = (f32x4){0.f, 0.f, 0.f, 0.f};

    const char* fsrc = (const char*)fc_img + (size_t)e * NSL * SLICE_B
                       + (size_t)half * NSTH * STEP_B16;
    const char* psrc = (const char*)pj_img + (size_t)e * NSL * SLICE_B
                       + (size_t)half * NSTH * STEP_B16;

    auto STAGE16 = [&](unsigned short* dst, const char* src) {
        #pragma unroll
        for (int i = 0; i < 4; ++i) {
            const int off = i * 4096 + tid * 16;
            gld16((char*)dst + off, src + off);
        }
    };

    auto FC_HS = [&](const unsigned short* bF) {
        f32x4 accF[2];
        accF[0] = (f32x4){0.f, 0.f, 0.f, 0.f};
        accF[1] = (f32x4){0.f, 0.f, 0.f, 0.f};
        __builtin_amdgcn_s_setprio(1);
        #pragma unroll
        for (int ks = 0; ks < 8; ++ks) {
            #pragma unroll
            for (int ct = 0; ct < 2; ++ct) {
                const bf16x8 b = *(const bf16x8*)((const char*)bF +
                                   (((ct * 8 + ks) * 64 + lane) << 4));
                accF[ct] = __builtin_amdgcn_mfma_f32_16x16x32_bf16(aF[ks], b, accF[ct], 0, 0, 0);
            }
        }
        __builtin_amdgcn_s_setprio(0);
        #pragma unroll
        for (int ct = 0; ct < 2; ++ct) {
            #pragma unroll
            for (int r = 0; r < 4; ++r) {
                const int hr = w * 16 + kg * 4 + r;
                float v = fmaxf(accF[ct][r], 0.f); v *= v;
                const int byte = (hr * 64 + (ct * 16 + l15) * 2) ^ ((hr & 7) << 4);
                *(unsigned short*)((char*)Hsm + byte) = f2bf(v);
            }
        }
    };

    auto PJ_COMP = [&]() {
        const int ar = w * 16 + l15;
        const int abyte = (ar * 64 + kg * 16) ^ ((ar & 7) << 4);
        const bf16x8 av = *(const bf16x8*)((const char*)Hsm + abyte);
        __builtin_amdgcn_s_setprio(1);
        #pragma unroll
        for (int ct = 0; ct < 16; ++ct) {
            const bf16x8 b = *(const bf16x8*)((const char*)pjS +
                               ((ct * 64 + lane) << 4));
            accP[ct] = __builtin_amdgcn_mfma_f32_16x16x32_bf16(av, b, accP[ct], 0, 0, 0);
        }
        __builtin_amdgcn_s_setprio(0);
    };

    // phase rotation: co-resident blocks (consecutive slots) start at steps
    // 0/4/8/12; accP accumulation over steps is order-independent.
    const int ph = (blockIdx.x & 3) * 4;

    // prologue: stage fc(step ph)
    STAGE16(fc0, fsrc + (size_t)ph * STEP_B16);
    asm volatile("" ::: "memory");

    #pragma unroll 1
    for (int t = 0; t < NSTH; ++t) {
        const int cur = (ph + t) & (NSTH - 1);
        const int nxt = (ph + t + 1) & (NSTH - 1);
        __builtin_amdgcn_s_barrier();                        // B1 (pjS/Hsm WAR)
        STAGE16(pjS, psrc + (size_t)cur * STEP_B16);
        if (t + 1 < NSTH)
            STAGE16((t & 1) ? fc0 : fc1, fsrc + (size_t)nxt * STEP_B16);
        if (t + 1 < NSTH) { asm volatile("s_waitcnt vmcnt(8)" ::: "memory"); }
        else              { asm volatile("s_waitcnt vmcnt(4)" ::: "memory"); }
        FC_HS((t & 1) ? fc1 : fc0);
        if (t + 1 < NSTH) { asm volatile("s_waitcnt vmcnt(4)" ::: "memory"); }
        else              { asm volatile("s_waitcnt vmcnt(0)" ::: "memory"); }
        __builtin_amdgcn_s_barrier();                        // B2 (Hsm RAW)
        PJ_COMP();
    }

    // ---- plain coalesced stores into this half's Yp bank
    unsigned short* Yb = Yp + (size_t)half * YBANK;
    #pragma unroll
    for (int r = 0; r < 4; ++r) {
        const int m = tstart + w * 16 + kg * 4 + r;
        if (m < tend) {
            unsigned short* d2 = Yb + (size_t)(segbase + m) * C_DIM + l15 * 16;
            bf16x8 u0, u1;
            #pragma unroll
            for (int j = 0; j < 8; ++j) {
                u0[j] = (short)f2bf(accP[j][r]);
                u1[j] = (short)f2bf(accP[j + 8][r]);
            }
            *(bf16x8*)d2       = u0;
            *(bf16x8*)(d2 + 8) = u1;
        }
    }
}

// --------------------------------------------------------------- combine ----
__global__ __launch_bounds__(256)
void combine_kernel(const unsigned short* __restrict__ Yp,
                    const int* __restrict__ seg,
                    const int* __restrict__ se, const int* __restrict__ sp,
                    const float* __restrict__ sw,
                    float* __restrict__ out)
{
    const int t = blockIdx.x * 256 + threadIdx.x;
    const int n = t >> 5;
    const int c0 = (t & 31) * 8;

    const unsigned short* Y0 = Yp;
    const unsigned short* Y1 = Yp + YBANK;

    float acc[8];
    {
        const bf16x8 ya = *(const bf16x8*)(Y0 + (size_t)n * C_DIM + c0);
        const bf16x8 yb = *(const bf16x8*)(Y1 + (size_t)n * C_DIM + c0);
        #pragma unroll
        for (int i = 0; i < 8; ++i)
            acc[i] = 0.25f * (bf2f((unsigned short)ya[i]) + bf2f((unsigned short)yb[i]));
    }
    #pragma unroll
    for (int k = 0; k < 3; ++k) {
        const int e = se[n * 3 + k];
        const int row = seg[e + 1] + sp[n * 3 + k];
        const float wgt = sw[n * 3 + k];
        const bf16x8 ya = *(const bf16x8*)(Y0 + (size_t)row * C_DIM + c0);
        const bf16x8 yb = *(const bf16x8*)(Y1 + (size_t)row * C_DIM + c0);
        #pragma unroll
        for (int i = 0; i < 8; ++i)
            acc[i] = fmaf(wgt, bf2f((unsigned short)ya[i]) + bf2f((unsigned short)yb[i]), acc[i]);
    }
    float4 o0 = make_float4(acc[0], acc[1], acc[2], acc[3]);
    float4 o1 = make_float4(acc[4], acc[5], acc[6], acc[7]);
    *(float4*)(out + (size_t)n * C_DIM + c0)     = o0;
    *(float4*)(out + (size_t)n * C_DIM + c0 + 4) = o1;
}

// ---------------------------------------------------------------- launch ----
extern "C" void kernel_launch(void* const* d_in, const int* in_sizes, int n_in,
                              void* d_out, int out_size, void* d_ws, size_t ws_size,
                              hipStream_t stream) {
    const float* x     = (const float*)d_in[0];
    const float* Wg    = (const float*)d_in[1];
    const float* Wfc   = (const float*)d_in[2];
    const float* Wpj   = (const float*)d_in[3];
    const float* ebias = (const float*)d_in[4];

    float* out = (float*)d_out;                       // [N, C]
    float* rw  = out + (size_t)N_TOK * C_DIM;         // [N, 32]

    char* ws = (char*)d_ws;
    int*          cnt  = (int*)ws;                                 ws += 256;
    int*          seg  = (int*)ws;                                 ws += 256;
    unsigned int* map  = (unsigned int*)ws;                        ws += MAPSLOTS * 4;
    int*   toks = (int*)ws;                                        ws += (size_t)E_RT * N_TOK * 4;
    int*   se   = (int*)ws;                                        ws += (size_t)N_TOK * 3 * 4;
    int*   sp   = (int*)ws;                                        ws += (size_t)N_TOK * 3 * 4;
    float* sw   = (float*)ws;                                      ws += (size_t)N_TOK * 3 * 4;
    unsigned short* xb      = (unsigned short*)ws;                 ws += (size_t)N_TOK * C_DIM * 2;
    unsigned short* fc_img  = (unsigned short*)ws;                 ws += (size_t)E_ALL * C_DIM * H_DIM * 2;
    unsigned short* pj_img  = (unsigned short*)ws;                 ws += (size_t)E_ALL * C_DIM * H_DIM * 2;
    unsigned short* Yp      = (unsigned short*)ws;                 // 2 banks ~34.5 MB

    hipMemsetAsync(cnt, 0, 256, stream);
    prep_gate<<<768, 256, 0, stream>>>(x, Wg, ebias, rw, cnt, toks, se, sp, sw,
                                       xb, Wfc, Wpj, fc_img, pj_img);
    finalize<<<1, 64, 0, stream>>>(cnt, seg, map);
    expert_kernel<<<MAPSLOTS, 256, 0, stream>>>(
        xb, fc_img, pj_img, cnt, seg, toks, map, Yp);
    combine_kernel<<<(N_TOK * 32) / 256, 256, 0, stream>>>(Yp, seg, se, sp, sw, out);
}

// Round 20
// 133.245 us; speedup vs baseline: 1.1260x; 1.1260x over previous
//
#include <hip/hip_runtime.h>
#include <hip/hip_bf16.h>
#include <cfloat>

#define N_TOK 8192
#define C_DIM 256
#define H_DIM 1024
#define E_ALL 32
#define E_RT  31
#define HS    128                     // h per image slice (prep granularity)
#define NSL   8                       // slices
#define TN    64                      // tokens per block (4 waves x 16)
#define HC2   32                      // h per step
#define NSTH  16                      // steps per H-half job
#define STEP_B16 16384                // bytes per weight-matrix step chunk
#define SLICE_B (HS * C_DIM * 2)      // 64 KB per slice
#define TG    32                      // tokens per gate block

// Yp geometry: 2 H-half banks of unweighted partials
#define YROWS 35072
#define YBANK ((size_t)YROWS * C_DIM)

// XCD-aware map geometry: slot s runs on XCD s%8 (round-robin dispatch)
#define NQ      8
#define QCAP    160
#define TAILN   256
#define MAPSLOTS (NQ * QCAP + TAILN)  // 1536

typedef __attribute__((ext_vector_type(8))) short bf16x8;
typedef __attribute__((ext_vector_type(4))) float f32x4;

__device__ __forceinline__ unsigned short f2bf(float f) {
    return __builtin_bit_cast(unsigned short, __float2bfloat16(f));
}
__device__ __forceinline__ float bf2f(unsigned short u) {
    unsigned int x = ((unsigned int)u) << 16;
    return __builtin_bit_cast(float, x);
}
__device__ __forceinline__ void gld16(void* lds, const void* g) {
    __builtin_amdgcn_global_load_lds(
        (const __attribute__((address_space(1))) void*)g,
        (__attribute__((address_space(3))) void*)lds, 16, 0, 0);
}

// ---------------------------------------------------------- fused front-end -
__device__ __forceinline__
void gate_body(char* smem, int blk,
               const float* __restrict__ x, const float* __restrict__ Wg,
               const float* __restrict__ ebias,
               float* __restrict__ rw, int* __restrict__ cnt,
               int* __restrict__ toks,
               int* __restrict__ se, int* __restrict__ sp, float* __restrict__ sw,
               unsigned short* __restrict__ xb)
{
    float* WgL = (float*)smem;                               // 32 KB [c*32+e]
    float (*xsW)[C_DIM] = (float(*)[C_DIM])(smem + 32768);   // 4 KB
    int*   lcnt = (int*)(smem + 36864);
    int*   gbase = lcnt + 32;
    int*   tokE  = gbase + 32;
    int*   tokLP = tokE + 96;
    float* tokW  = (float*)(tokLP + 96);

    const int n0  = blk * TG;
    const int tid = threadIdx.x;
    const int w    = tid >> 6;
    const int lane = tid & 63;
    const int e    = lane & 31;
    const int h    = lane >> 5;

    for (int i = tid; i < C_DIM * E_RT / 4; i += 256) {
        const float4 v = ((const float4*)Wg)[i];
        const int l = i * 4;
        #pragma unroll
        for (int j = 0; j < 4; ++j) {
            const int lj = l + j, c = lj / E_RT, ee = lj - c * E_RT;
            const float vv = (j == 0) ? v.x : (j == 1) ? v.y : (j == 2) ? v.z : v.w;
            WgL[c * 32 + ee] = vv;
        }
    }
    if (tid < E_RT) lcnt[tid] = 0;
    __syncthreads();

    const float eb = (e < E_RT) ? ebias[e] : 0.f;

    #pragma unroll 1
    for (int j = 0; j < 8; ++j) {
        const int n = n0 + w * 8 + j;
        const float4 xv = ((const float4*)(x + (size_t)n * C_DIM))[lane];
        ((float4*)xsW[w])[lane] = xv;
        {
            ushort4 b;
            b.x = f2bf(xv.x); b.y = f2bf(xv.y); b.z = f2bf(xv.z); b.w = f2bf(xv.w);
            ((ushort4*)(xb + (size_t)n * C_DIM))[lane] = b;
        }
        float p0 = 0.f, p1 = 0.f, p2 = 0.f, p3 = 0.f;
        const int cb = h * 128;
        #pragma unroll
        for (int c4 = 0; c4 < 32; ++c4) {
            const float4 xq = *(const float4*)&xsW[w][cb + c4 * 4];
            p0 = fmaf(xq.x, WgL[(cb + c4 * 4 + 0) * 32 + e], p0);
            p1 = fmaf(xq.y, WgL[(cb + c4 * 4 + 1) * 32 + e], p1);
            p2 = fmaf(xq.z, WgL[(cb + c4 * 4 + 2) * 32 + e], p2);
            p3 = fmaf(xq.w, WgL[(cb + c4 * 4 + 3) * 32 + e], p3);
        }
        float part = (p0 + p1) + (p2 + p3);
        part += __shfl_xor(part, 32);
        const float logit = (lane < E_RT) ? part : -FLT_MAX;

        float m = logit;
        for (int off = 32; off; off >>= 1) m = fmaxf(m, __shfl_xor(m, off));
        const float ev = (lane < E_RT) ? expf(logit - m) : 0.f;
        float sum = ev;
        for (int off = 32; off; off >>= 1) sum += __shfl_xor(sum, off);
        const float gate = ev / sum;
        const float biased = (lane < E_RT) ? gate + eb : -FLT_MAX;

        float val[3]; int idx[3];
        float cur = biased;
        #pragma unroll
        for (int k = 0; k < 3; ++k) {
            float mk = cur;
            for (int off = 32; off; off >>= 1) mk = fmaxf(mk, __shfl_xor(mk, off));
            unsigned long long ball = __ballot(cur == mk && lane < E_RT);
            int sel = __ffsll(ball) - 1;
            val[k] = mk; idx[k] = sel;
            if (lane == sel) cur = -FLT_MAX;
        }

        const float st = val[0] + val[1] + val[2];
        const float wr0 = val[0] / st * 0.75f;
        const float wr1 = val[1] / st * 0.75f;
        const float wr2 = val[2] / st * 0.75f;

        if (lane < E_ALL) {
            float v = 0.f;
            if (lane == 0)          v = 0.25f;
            if (lane == idx[0] + 1) v = wr0;
            if (lane == idx[1] + 1) v = wr1;
            if (lane == idx[2] + 1) v = wr2;
            rw[(size_t)n * E_ALL + lane] = v;
        }

        if (lane == 0) {
            const float wv[3] = {wr0, wr1, wr2};
            const int tl = w * 8 + j;
            #pragma unroll
            for (int k = 0; k < 3; ++k) {
                const int lp = atomicAdd(&lcnt[idx[k]], 1);
                tokE[tl * 3 + k] = idx[k];
                tokLP[tl * 3 + k] = lp;
                tokW[tl * 3 + k] = wv[k];
            }
        }
    }

    __syncthreads();
    if (tid < E_RT) gbase[tid] = atomicAdd(&cnt[tid], lcnt[tid]);
    __syncthreads();

    if (tid < TG) {
        const int n = n0 + tid;
        #pragma unroll
        for (int k = 0; k < 3; ++k) {
            const int e31 = tokE[tid * 3 + k];
            const int pos = gbase[e31] + tokLP[tid * 3 + k];
            toks[e31 * N_TOK + pos] = n;
            se[n * 3 + k] = e31;
            sp[n * 3 + k] = pos;
            sw[n * 3 + k] = tokW[tid * 3 + k];
        }
    }
}

__device__ __forceinline__
void prep_fc_body(char* smem, int unit,
                  const float* __restrict__ Wfc, unsigned short* __restrict__ img)
{
    const int s = unit & 7, e = unit >> 3;
    const int h0 = s * HS;
    unsigned short* tb = (unsigned short*)smem;
    const int tid = threadIdx.x;
    #pragma unroll
    for (int i = 0; i < 32; ++i) {
        const int fidx = i * 1024 + tid * 4;
        const int c = fidx >> 7, hh = fidx & 127;
        const float4 v = *(const float4*)(Wfc + ((size_t)e * C_DIM + c) * H_DIM + h0 + hh);
        ushort4 b;
        b.x = f2bf(v.x); b.y = f2bf(v.y); b.z = f2bf(v.z); b.w = f2bf(v.w);
        *(ushort4*)(tb + c * HS + hh) = b;
    }
    __syncthreads();
    const int lane = tid & 63, w = tid >> 6;
    const int l15 = lane & 15, kg = lane >> 4;
    unsigned short* dst = img + ((size_t)e * NSL + s) * (SLICE_B / 2);
    for (int li = w; li < 64; li += 4) {
        const int ct = li >> 3, ks = li & 7;      // ct-major
        bf16x8 v;
        #pragma unroll
        for (int j = 0; j < 8; ++j)
            v[j] = (short)tb[(ks * 32 + kg * 8 + j) * HS + ct * 16 + l15];
        *(bf16x8*)(dst + (size_t)li * 512 + lane * 8) = v;
    }
}

__device__ __forceinline__
void prep_pj_body(char* smem, int unit,
                  const float* __restrict__ Wpj, unsigned short* __restrict__ img)
{
    const int s = unit & 7, e = unit >> 3;
    const int h0 = s * HS;
    unsigned short* tb = (unsigned short*)smem;
    const int tid = threadIdx.x;
    #pragma unroll
    for (int i = 0; i < 32; ++i) {
        const int fidx = i * 1024 + tid * 4;
        const int r = fidx >> 8, cc = fidx & 255;
        const float4 v = *(const float4*)(Wpj + ((size_t)e * H_DIM + h0 + r) * C_DIM + cc);
        ushort4 b;
        b.x = f2bf(v.x); b.y = f2bf(v.y); b.z = f2bf(v.z); b.w = f2bf(v.w);
        *(ushort4*)(tb + r * C_DIM + cc) = b;
    }
    __syncthreads();
    const int lane = tid & 63, w = tid >> 6;
    const int l15 = lane & 15, kg = lane >> 4;
    unsigned short* dst = img + ((size_t)e * NSL + s) * (SLICE_B / 2);
    for (int li = w; li < 64; li += 4) {
        const int ks = li >> 4, ct = li & 15;
        bf16x8 v;
        #pragma unroll
        for (int j = 0; j < 8; ++j)
            v[j] = (short)tb[(ks * 32 + kg * 8 + j) * C_DIM + ct + l15 * 16];
        *(bf16x8*)(dst + (size_t)li * 512 + lane * 8) = v;
    }
}

__global__ __launch_bounds__(256)
void prep_gate(const float* __restrict__ x, const float* __restrict__ Wg,
               const float* __restrict__ ebias,
               float* __restrict__ rw, int* __restrict__ cnt,
               int* __restrict__ toks,
               int* __restrict__ se, int* __restrict__ sp, float* __restrict__ sw,
               unsigned short* __restrict__ xb,
               const float* __restrict__ Wfc, const float* __restrict__ Wpj,
               unsigned short* __restrict__ fc_img, unsigned short* __restrict__ pj_img)
{
    __shared__ char smem[65536];
    const int b = blockIdx.x;
    if (b < 256)      gate_body(smem, b, x, Wg, ebias, rw, cnt, toks, se, sp, sw, xb);
    else if (b < 512) prep_fc_body(smem, b - 256, Wfc, fc_img);
    else              prep_pj_body(smem, b - 512, Wpj, pj_img);
}

// ---- seg + XCD-aware map of (expert, 64-tok tile, H-half) jobs -------------
__global__ __launch_bounds__(64)
void finalize(const int* __restrict__ cnt, int* __restrict__ seg,
              unsigned int* __restrict__ map) {
    __shared__ int ntS[E_RT];
    __shared__ int qaS[E_RT * 2];
    __shared__ int jsS[E_RT * 2];
    __shared__ int segS[E_ALL];
    __shared__ int jposS[NQ];
    __shared__ int spillS;

    const int tid = threadIdx.x;

    for (int s = tid; s < MAPSLOTS; s += 64) map[s] = 0xFFFFFFFFu;
    if (tid < E_RT) ntS[tid] = (cnt[tid] + TN - 1) / TN;
    if (tid == 0) spillS = NQ * QCAP;
    __syncthreads();

    if (tid == 0) {
        int b = N_TOK;
        segS[0] = 0;
        for (int i = 0; i < E_RT; ++i) { segS[i + 1] = b; b += (cnt[i] + 63) & ~63; }
        for (int q = 0; q < NQ; ++q) jposS[q] = (2 * N_TOK / TN) / NQ;   // 32
        for (int j2 = 0; j2 < E_RT * 2; ++j2) {
            const int i = j2 >> 1;
            int q = 0;
            for (int j = 1; j < NQ; ++j) if (jposS[j] < jposS[q]) q = j;
            qaS[j2] = q;
            jsS[j2] = jposS[q];
            jposS[q] += ntS[i];
        }
    }
    __syncthreads();

    if (tid < E_ALL) seg[tid] = segS[tid];

    for (int cmb = tid; cmb < 2 * N_TOK / TN; cmb += 64) {
        const unsigned v = ((unsigned)(cmb & 1) << 16) | (unsigned)(cmb >> 1);
        map[(cmb / NQ) * NQ + (cmb % NQ)] = v;
    }

    if (tid < E_RT * 2) {
        const int i = tid >> 1, hf = tid & 1;
        const int q = qaS[tid], js = jsS[tid], ntv = ntS[i];
        for (int t = 0; t < ntv; ++t) {
            const unsigned v = ((unsigned)hf << 16) |
                               ((unsigned)(i + 1) << 8) | (unsigned)t;
            const int jrow = js + t;
            if (jrow < QCAP) map[jrow * NQ + q] = v;
            else {
                const int s = atomicAdd(&spillS, 1);
                if (s < MAPSLOTS) map[s] = v;
            }
        }
    }
}

// --- experts: R16-verbatim (fc dbuf + pj single, 52 KB, 3 blocks/CU,
//     fixed counted-vmcnt loop body + peeled epilogue) -----------------------
__global__ __launch_bounds__(256)
void expert_kernel(const unsigned short* __restrict__ xb,
                   const unsigned short* __restrict__ fc_img,
                   const unsigned short* __restrict__ pj_img,
                   const int* __restrict__ cnt,
                   const int* __restrict__ seg,
                   const int* __restrict__ toks,
                   const unsigned int* __restrict__ map,
                   unsigned short* __restrict__ Yp)
{
    const unsigned int mp = map[blockIdx.x];
    if (mp == 0xFFFFFFFFu) return;
    const int half = (mp >> 16) & 1;
    const int e = (mp >> 8) & 255;
    const int tstart = (int)(mp & 255u) * TN;
    const int count = (e == 0) ? N_TOK : cnt[e - 1];
    const int tend = min(tstart + TN, count);
    const int segbase = seg[e];

    __shared__ unsigned short fc0[STEP_B16 / 2];   // 16 KB
    __shared__ unsigned short fc1[STEP_B16 / 2];   // 16 KB
    __shared__ unsigned short pjS[STEP_B16 / 2];   // 16 KB (single buffer)
    __shared__ unsigned short Hsm[TN * HC2];       // 4 KB, wave-local rows

    const int tid  = threadIdx.x;
    const int lane = tid & 63;
    const int w    = tid >> 6;
    const int l15  = lane & 15;
    const int kg   = lane >> 4;

    const int p = tstart + w * 16 + l15;
    int tok = 0;
    if (p < tend) tok = (e == 0) ? p : toks[(e - 1) * N_TOK + p];

    bf16x8 aF[8];
    {
        const unsigned short* xr = xb + (size_t)tok * C_DIM + kg * 8;
        #pragma unroll
        for (int ks = 0; ks < 8; ++ks)
            aF[ks] = *(const bf16x8*)(xr + ks * 32);
    }

    f32x4 accP[16];
    #pragma unroll
    for (int i = 0; i < 16; ++i) accP[i] = (f32x4){0.f, 0.f, 0.f, 0.f};

    const char* fsrc = (const char*)fc_img + (size_t)e * NSL * SLICE_B
                       + (size_t)half * NSTH * STEP_B16;
    const char* psrc = (const char*)pj_img + (size_t)e * NSL * SLICE_B
                       + (size_t)half * NSTH * STEP_B16;

    auto STAGE16 = [&](unsigned short* dst, const char* src) {
        #pragma unroll
        for (int i = 0; i < 4; ++i) {
            const int off = i * 4096 + tid * 16;
            gld16((char*)dst + off, src + off);
        }
    };

    auto FC_HS = [&](const unsigned short* bF) {
        f32x4 accF[2];
        accF[0] = (f32x4){0.f, 0.f, 0.f, 0.f};
        accF[1] = (f32x4){0.f, 0.f, 0.f, 0.f};
        __builtin_amdgcn_s_setprio(1);
        #pragma unroll
        for (int ks = 0; ks < 8; ++ks) {
            #pragma unroll
            for (int ct = 0; ct < 2; ++ct) {
                const bf16x8 b = *(const bf16x8*)((const char*)bF +
                                   (((ct * 8 + ks) * 64 + lane) << 4));
                accF[ct] = __builtin_amdgcn_mfma_f32_16x16x32_bf16(aF[ks], b, accF[ct], 0, 0, 0);
            }
        }
        __builtin_amdgcn_s_setprio(0);
        #pragma unroll
        for (int ct = 0; ct < 2; ++ct) {
            #pragma unroll
            for (int r = 0; r < 4; ++r) {
                const int hr = w * 16 + kg * 4 + r;
                float v = fmaxf(accF[ct][r], 0.f); v *= v;
                const int byte = (hr * 64 + (ct * 16 + l15) * 2) ^ ((hr & 7) << 4);
                *(unsigned short*)((char*)Hsm + byte) = f2bf(v);
            }
        }
    };

    auto PJ_COMP = [&]() {
        const int ar = w * 16 + l15;
        const int abyte = (ar * 64 + kg * 16) ^ ((ar & 7) << 4);
        const bf16x8 av = *(const bf16x8*)((const char*)Hsm + abyte);
        __builtin_amdgcn_s_setprio(1);
        #pragma unroll
        for (int ct = 0; ct < 16; ++ct) {
            const bf16x8 b = *(const bf16x8*)((const char*)pjS +
                               ((ct * 64 + lane) << 4));
            accP[ct] = __builtin_amdgcn_mfma_f32_16x16x32_bf16(av, b, accP[ct], 0, 0, 0);
        }
        __builtin_amdgcn_s_setprio(0);
    };

    // prologue: stage fc(0) only
    STAGE16(fc0, fsrc);
    asm volatile("" ::: "memory");

    #pragma unroll 1
    for (int t = 0; t < NSTH - 1; ++t) {
        __builtin_amdgcn_s_barrier();                        // B1 (pjS/Hsm WAR)
        STAGE16(pjS, psrc + (size_t)t * STEP_B16);
        STAGE16((t & 1) ? fc0 : fc1, fsrc + (size_t)(t + 1) * STEP_B16);
        asm volatile("s_waitcnt vmcnt(8)" ::: "memory");     // fc(t) landed
        FC_HS((t & 1) ? fc1 : fc0);
        asm volatile("s_waitcnt vmcnt(4)" ::: "memory");     // pj(t) landed
        __builtin_amdgcn_s_barrier();                        // B2
        PJ_COMP();
    }
    // epilogue: t = NSTH-1 (odd -> fc1), no fc prefetch
    __builtin_amdgcn_s_barrier();
    STAGE16(pjS, psrc + (size_t)(NSTH - 1) * STEP_B16);
    asm volatile("s_waitcnt vmcnt(4)" ::: "memory");         // fc(15) landed
    FC_HS(fc1);
    asm volatile("s_waitcnt vmcnt(0)" ::: "memory");         // pj(15) landed
    __builtin_amdgcn_s_barrier();
    PJ_COMP();

    // ---- plain coalesced stores into this half's Yp bank
    unsigned short* Yb = Yp + (size_t)half * YBANK;
    #pragma unroll
    for (int r = 0; r < 4; ++r) {
        const int m = tstart + w * 16 + kg * 4 + r;
        if (m < tend) {
            unsigned short* d2 = Yb + (size_t)(segbase + m) * C_DIM + l15 * 16;
            bf16x8 u0, u1;
            #pragma unroll
            for (int j = 0; j < 8; ++j) {
                u0[j] = (short)f2bf(accP[j][r]);
                u1[j] = (short)f2bf(accP[j + 8][r]);
            }
            *(bf16x8*)d2       = u0;
            *(bf16x8*)(d2 + 8) = u1;
        }
    }
}

// --------------------------------------------------------------- combine ----
__global__ __launch_bounds__(256)
void combine_kernel(const unsigned short* __restrict__ Yp,
                    const int* __restrict__ seg,
                    const int* __restrict__ se, const int* __restrict__ sp,
                    const float* __restrict__ sw,
                    float* __restrict__ out)
{
    const int t = blockIdx.x * 256 + threadIdx.x;
    const int n = t >> 5;
    const int c0 = (t & 31) * 8;

    const unsigned short* Y0 = Yp;
    const unsigned short* Y1 = Yp + YBANK;

    float acc[8];
    {
        const bf16x8 ya = *(const bf16x8*)(Y0 + (size_t)n * C_DIM + c0);
        const bf16x8 yb = *(const bf16x8*)(Y1 + (size_t)n * C_DIM + c0);
        #pragma unroll
        for (int i = 0; i < 8; ++i)
            acc[i] = 0.25f * (bf2f((unsigned short)ya[i]) + bf2f((unsigned short)yb[i]));
    }
    #pragma unroll
    for (int k = 0; k < 3; ++k) {
        const int e = se[n * 3 + k];
        const int row = seg[e + 1] + sp[n * 3 + k];
        const float wgt = sw[n * 3 + k];
        const bf16x8 ya = *(const bf16x8*)(Y0 + (size_t)row * C_DIM + c0);
        const bf16x8 yb = *(const bf16x8*)(Y1 + (size_t)row * C_DIM + c0);
        #pragma unroll
        for (int i = 0; i < 8; ++i)
            acc[i] = fmaf(wgt, bf2f((unsigned short)ya[i]) + bf2f((unsigned short)yb[i]), acc[i]);
    }
    float4 o0 = make_float4(acc[0], acc[1], acc[2], acc[3]);
    float4 o1 = make_float4(acc[4], acc[5], acc[6], acc[7]);
    *(float4*)(out + (size_t)n * C_DIM + c0)     = o0;
    *(float4*)(out + (size_t)n * C_DIM + c0 + 4) = o1;
}

// ---------------------------------------------------------------- launch ----
extern "C" void kernel_launch(void* const* d_in, const int* in_sizes, int n_in,
                              void* d_out, int out_size, void* d_ws, size_t ws_size,
                              hipStream_t stream) {
    const float* x     = (const float*)d_in[0];
    const float* Wg    = (const float*)d_in[1];
    const float* Wfc   = (const float*)d_in[2];
    const float* Wpj   = (const float*)d_in[3];
    const float* ebias = (const float*)d_in[4];

    float* out = (float*)d_out;                       // [N, C]
    float* rw  = out + (size_t)N_TOK * C_DIM;         // [N, 32]

    char* ws = (char*)d_ws;
    int*          cnt  = (int*)ws;                                 ws += 256;
    int*          seg  = (int*)ws;                                 ws += 256;
    unsigned int* map  = (unsigned int*)ws;                        ws += MAPSLOTS * 4;
    int*   toks = (int*)ws;                                        ws += (size_t)E_RT * N_TOK * 4;
    int*   se   = (int*)ws;                                        ws += (size_t)N_TOK * 3 * 4;
    int*   sp   = (int*)ws;                                        ws += (size_t)N_TOK * 3 * 4;
    float* sw   = (float*)ws;                                      ws += (size_t)N_TOK * 3 * 4;
    unsigned short* xb      = (unsigned short*)ws;                 ws += (size_t)N_TOK * C_DIM * 2;
    unsigned short* fc_img  = (unsigned short*)ws;                 ws += (size_t)E_ALL * C_DIM * H_DIM * 2;
    unsigned short* pj_img  = (unsigned short*)ws;                 ws += (size_t)E_ALL * C_DIM * H_DIM * 2;
    unsigned short* Yp      = (unsigned short*)ws;                 // 2 banks ~34.5 MB

    hipMemsetAsync(cnt, 0, 256, stream);
    prep_gate<<<768, 256, 0, stream>>>(x, Wg, ebias, rw, cnt, toks, se, sp, sw,
                                       xb, Wfc, Wpj, fc_img, pj_img);
    finalize<<<1, 64, 0, stream>>>(cnt, seg, map);
    expert_kernel<<<MAPSLOTS, 256, 0, stream>>>(
        xb, fc_img, pj_img, cnt, seg, toks, map, Yp);
    combine_kernel<<<(N_TOK * 32) / 256, 256, 0, stream>>>(Yp, seg, se, sp, sw, out);
}